// Round 1
// baseline (2697.878 us; speedup 1.0000x reference)
//
#include <hip/hip_runtime.h>
#include <hip/hip_bf16.h>
#include <cstdint>

#define TT 300
#define NB 8

// SLAYER constants (double-rounded to f32, matching jnp f32 ops on python doubles)
static constexpr float D_SR  = 0.90483741803595957f;   // exp(-1/10)
static constexpr float B_SR  = 0.27182818284590454f;   // e*Ts/tau_sr
static constexpr float D_RF  = 0.36787944117144233f;   // exp(-1)
static constexpr float A_RF  = -54.365636569180902f;   // -2*theta*e
static constexpr float THETA_F = 10.0f;
static constexpr float PGAIN = 11.0f;                  // 1.1*theta

// K0: psp on input + transpose  in:[NS,T] (T contiguous) -> out:[T][NS]
__global__ void k_psp_tr(const float* __restrict__ in, float* __restrict__ out, int NS) {
    int i = blockIdx.x * blockDim.x + threadIdx.x;
    if (i >= NS) return;
    const float* x = in + (size_t)i * TT;
    float p = 0.f, q = 0.f;
    for (int t = 0; t < TT; ++t) {
        q = D_SR * (q + p);
        p = D_SR * p + x[t];
        out[(size_t)t * NS + i] = B_SR * q;
    }
}

// generic conv, pad=1, layout [T][N][C][H][W]
template<int CI, int CO, int KS, int HI, int WI, int HO, int WO>
__global__ void k_conv(const float* __restrict__ in, const float* __restrict__ w,
                       float* __restrict__ out) {
    int gid = blockIdx.x * blockDim.x + threadIdx.x;
    const int per_img = CO * HO * WO;
    const int total = TT * NB * per_img;
    if (gid >= total) return;
    int ow = gid % WO;
    int oh = (gid / WO) % HO;
    int oc = (gid / (WO * HO)) % CO;
    int tn = gid / per_img;                    // t*NB + n
    const float* ib = in + (size_t)tn * (CI * HI * WI);
    const float* wb = w + oc * (CI * KS * KS);
    float acc = 0.f;
    for (int ic = 0; ic < CI; ++ic) {
        const float* icb = ib + ic * HI * WI;
        const float* wc  = wb + ic * KS * KS;
        #pragma unroll
        for (int kh = 0; kh < KS; ++kh) {
            int ih = oh + kh - 1;
            if (ih < 0 || ih >= HI) continue;
            #pragma unroll
            for (int kw = 0; kw < KS; ++kw) {
                int iw = ow + kw - 1;
                if (iw < 0 || iw >= WI) continue;
                acc += icb[ih * WI + iw] * wc[kh * KS + kw];
            }
        }
    }
    out[(size_t)gid] = acc;
}

// spike with refractory feedback, in place on [T][NS]
__global__ void k_spike(float* __restrict__ buf, int NS) {
    int i = blockIdx.x * blockDim.x + threadIdx.x;
    if (i >= NS) return;
    float p = 0.f, q = 0.f;
    for (int t = 0; t < TT; ++t) {
        float u = buf[(size_t)t * NS + i];
        q = D_RF * (q + p);
        float v = u + A_RF * q;
        float s = (v >= THETA_F) ? 1.0f : 0.0f;
        p = D_RF * p + s;
        buf[(size_t)t * NS + i] = s;
    }
}

// fused 2x2 sum-pool (*1.1*theta) + psp:  in [T][N][C][HI][WI] -> out [T][N][C][HI/2][WI/2]
template<int C, int HI, int WI>
__global__ void k_pool_psp(const float* __restrict__ in, float* __restrict__ out) {
    const int HO = HI / 2, WO = WI / 2;
    const int M = NB * C * HO * WO;
    const int NS_in = NB * C * HI * WI;
    int i = blockIdx.x * blockDim.x + threadIdx.x;
    if (i >= M) return;
    int j  = i % WO;
    int r  = i / WO;
    int ii = r % HO;
    int nc = r / HO;                              // n*C + c
    int base0 = (nc * HI + 2 * ii) * WI + 2 * j;
    float p = 0.f, q = 0.f;
    for (int t = 0; t < TT; ++t) {
        const float* b = in + (size_t)t * NS_in + base0;
        float x = (b[0] + b[1] + b[WI] + b[WI + 1]) * PGAIN;
        q = D_SR * (q + p);
        p = D_SR * p + x;
        out[(size_t)t * M + i] = B_SR * q;
    }
}

// psp in place on [T][NS]
__global__ void k_psp_ip(float* __restrict__ buf, int NS) {
    int i = blockIdx.x * blockDim.x + threadIdx.x;
    if (i >= NS) return;
    float p = 0.f, q = 0.f;
    for (int t = 0; t < TT; ++t) {
        float x = buf[(size_t)t * NS + i];
        q = D_SR * (q + p);
        p = D_SR * p + x;
        buf[(size_t)t * NS + i] = B_SR * q;
    }
}

// dense over 64*7*7=3136 per (t,n,o); in [T][N][3136] -> G[t*80 + n*10 + o]
__global__ void k_dense(const float* __restrict__ in, const float* __restrict__ w,
                        float* __restrict__ out) {
    int gid = blockIdx.x * blockDim.x + threadIdx.x;
    if (gid >= 10 * TT * NB) return;
    int o  = gid / (TT * NB);
    int tn = gid % (TT * NB);                     // t*NB + n
    const float* ib = in + (size_t)tn * 3136;
    const float* wb = w + o * 3136;
    float acc = 0.f;
    for (int k = 0; k < 3136; ++k) acc += ib[k] * wb[k];
    out[tn * 10 + o] = acc;                       // = t*80 + n*10 + o
}

// final spike on [T][80], scatter to out [N][10][T] (T contiguous)
__global__ void k_spike_out(const float* __restrict__ G, float* __restrict__ out) {
    int i = threadIdx.x;
    if (i >= 80) return;
    float p = 0.f, q = 0.f;
    for (int t = 0; t < TT; ++t) {
        float u = G[t * 80 + i];
        q = D_RF * (q + p);
        float v = u + A_RF * q;
        float s = (v >= THETA_F) ? 1.0f : 0.0f;
        p = D_RF * p + s;
        out[(size_t)i * TT + t] = s;              // i = n*10+o -> [n][o][t]
    }
}

static inline int cdiv(int a, int b) { return (a + b - 1) / b; }

extern "C" void kernel_launch(void* const* d_in, const int* in_sizes, int n_in,
                              void* d_out, int out_size, void* d_ws, size_t ws_size,
                              hipStream_t stream) {
    const float* x  = (const float*)d_in[0];   // [8,1,30,30,300]
    const float* w1 = (const float*)d_in[1];   // [16,1,5,5]
    const float* w2 = (const float*)d_in[2];   // [32,16,3,3]
    const float* w3 = (const float*)d_in[3];   // [64,32,3,3]
    const float* wf = (const float*)d_in[4];   // [10,64,7,7]
    float* out = (float*)d_out;                // [8,10,300]
    float* ws  = (float*)d_ws;

    // workspace layout (floats)
    float* A  = ws;                 // [300][7200]    psp(input), transposed
    float* Bb = A  + 2160000;       // [300][100352]  u1/s1; reused as conv2 out
    float* Cc = Bb + 30105600;      // [300][25088]   s2/P2; reused as conv3 out
    float* Ee = Cc + 7526400;       // [300][12544]   s4/P4
    float* Gg = Ee + 3763200;       // [300][80]      dense out
    // total: 43,579,200 floats = 174.3 MB

    const int B256 = 256;
    // L0: psp + transpose
    k_psp_tr<<<cdiv(7200, B256), B256, 0, stream>>>(x, A, 7200);
    // L1: conv1 5x5 pad1, 1->16, 30x30 -> 28x28
    k_conv<1, 16, 5, 30, 30, 28, 28><<<cdiv(30105600, B256), B256, 0, stream>>>(A, w1, Bb);
    k_spike<<<cdiv(100352, B256), B256, 0, stream>>>(Bb, 100352);
    // L2: pool+psp -> spike
    k_pool_psp<16, 28, 28><<<cdiv(25088, B256), B256, 0, stream>>>(Bb, Cc);
    k_spike<<<cdiv(25088, B256), B256, 0, stream>>>(Cc, 25088);
    // L3: psp -> conv2 3x3 pad1, 16->32, 14x14 -> spike
    k_psp_ip<<<cdiv(25088, B256), B256, 0, stream>>>(Cc, 25088);
    k_conv<16, 32, 3, 14, 14, 14, 14><<<cdiv(15052800, B256), B256, 0, stream>>>(Cc, w2, Bb);
    k_spike<<<cdiv(50176, B256), B256, 0, stream>>>(Bb, 50176);
    // L4: pool+psp -> spike
    k_pool_psp<32, 14, 14><<<cdiv(12544, B256), B256, 0, stream>>>(Bb, Ee);
    k_spike<<<cdiv(12544, B256), B256, 0, stream>>>(Ee, 12544);
    // L5: psp -> conv3 3x3 pad1, 32->64, 7x7 -> spike
    k_psp_ip<<<cdiv(12544, B256), B256, 0, stream>>>(Ee, 12544);
    k_conv<32, 64, 3, 7, 7, 7, 7><<<cdiv(7526400, B256), B256, 0, stream>>>(Ee, w3, Cc);
    k_spike<<<cdiv(25088, B256), B256, 0, stream>>>(Cc, 25088);
    // L6: psp -> dense -> spike -> out
    k_psp_ip<<<cdiv(25088, B256), B256, 0, stream>>>(Cc, 25088);
    k_dense<<<cdiv(24000, B256), B256, 0, stream>>>(Cc, wf, Gg);
    k_spike_out<<<1, 128, 0, stream>>>(Gg, out);
}

// Round 2
// 385.904 us; speedup vs baseline: 6.9911x; 6.9911x over previous
//
#include <hip/hip_runtime.h>
#include <hip/hip_bf16.h>
#include <cstdint>

#define TT 300
#define NB 8

static constexpr float D_SR  = 0.90483741803595957f;   // exp(-1/10)
static constexpr float B_SR  = 0.27182818284590454f;   // e/10
static constexpr float D_RF  = 0.36787944117144233f;   // exp(-1)
static constexpr float A_RF  = -54.365636569180902f;   // -2*theta*e
static constexpr float THETA_F = 10.0f;
static constexpr float PGAIN = 11.0f;                  // 1.1*theta

// ---- weight transpose: [oc][s] -> [s][oc] for scalar-load-friendly access
__global__ void k_wtr(const float* __restrict__ w1, const float* __restrict__ w2,
                      const float* __restrict__ w3, float* __restrict__ t1,
                      float* __restrict__ t2, float* __restrict__ t3) {
    int g = blockIdx.x * blockDim.x + threadIdx.x;
    if (g < 400) {                       // conv1: 16 oc x 25
        int oc = g / 25, s = g % 25;
        t1[s * 16 + oc] = w1[g];
    } else if (g < 400 + 4608) {         // conv2: 32 oc x 144
        int h = g - 400, oc = h / 144, s = h % 144;
        t2[s * 32 + oc] = w2[h];
    } else if (g < 400 + 4608 + 18432) { // conv3: 64 oc x 288
        int h = g - 5008, oc = h / 288, s = h % 288;
        t3[s * 64 + oc] = w3[h];
    }
}

// ---- psp on input + transpose  in:[NS][T] -> out:[T][NS], prefetched float4
__global__ void k_psp_tr(const float* __restrict__ in, float* __restrict__ out, int NS) {
    int i = blockIdx.x * blockDim.x + threadIdx.x;
    if (i >= NS) return;
    const float4* x4 = (const float4*)(in + (size_t)i * TT);
    constexpr int G4 = 5;               // 5 float4 = 20 timesteps per group
    constexpr int NG = TT / (4 * G4);   // 15 groups
    float4 A[G4], B[G4];
    #pragma unroll
    for (int u = 0; u < G4; ++u) A[u] = x4[u];
    float p = 0.f, q = 0.f;
    for (int g = 0; g < NG; ++g) {
        if (g + 1 < NG) {
            #pragma unroll
            for (int u = 0; u < G4; ++u) B[u] = x4[(g + 1) * G4 + u];
        }
        int t0 = g * G4 * 4;
        #pragma unroll
        for (int u = 0; u < G4; ++u) {
            float xs[4] = {A[u].x, A[u].y, A[u].z, A[u].w};
            #pragma unroll
            for (int e = 0; e < 4; ++e) {
                q = D_SR * (q + p);
                p = D_SR * p + xs[e];
                out[(size_t)(t0 + u * 4 + e) * NS + i] = B_SR * q;
            }
        }
        #pragma unroll
        for (int u = 0; u < G4; ++u) A[u] = B[u];
    }
}

// ---- tiled conv: one WG per (t,n); LDS-padded input; SGPR weights
// wave handles OCW oc; each lane handles J pixel-groups of 49
template<int CI, int CO, int KS, int HI, int WI, int HO, int WO, int OCW, int J>
__global__ __launch_bounds__(256) void k_conv(const float* __restrict__ in,
                                              const float* __restrict__ wT,
                                              float* __restrict__ out) {
    constexpr int PW = WI + 2, PH = HI + 2, PST = PH * PW;
    __shared__ float lds[CI * PST];
    const int tid = threadIdx.x;
    const int tn  = blockIdx.x;
    const float* img = in + (size_t)tn * (CI * HI * WI);
    for (int idx = tid; idx < CI * PST; idx += 256) lds[idx] = 0.f;
    __syncthreads();
    for (int idx = tid; idx < CI * HI * WI; idx += 256) {
        int ic = idx / (HI * WI), rem = idx % (HI * WI);
        int r = rem / WI, c = rem % WI;
        lds[ic * PST + (r + 1) * PW + (c + 1)] = img[idx];
    }
    __syncthreads();

    const int wave = __builtin_amdgcn_readfirstlane(tid >> 6);
    const int lane = tid & 63;
    const int l = lane < 49 ? lane : 48;
    const int oc0 = (CO == OCW) ? 0 : wave * OCW;

    int pbase[J];
    #pragma unroll
    for (int j = 0; j < J; ++j) {
        int g = (CO == OCW) ? (wave * J + j) : j;
        int px = g * 49 + l;
        pbase[j] = (px / WO) * PW + (px % WO);
    }
    float acc[J * OCW];
    #pragma unroll
    for (int a = 0; a < J * OCW; ++a) acc[a] = 0.f;

    for (int ic = 0; ic < CI; ++ic) {
        #pragma unroll
        for (int kh = 0; kh < KS; ++kh) {
            #pragma unroll
            for (int kw = 0; kw < KS; ++kw) {
                const int step = (ic * KS + kh) * KS + kw;
                const float4* wv = reinterpret_cast<const float4*>(wT + step * CO + oc0);
                float4 wr[OCW / 4];
                #pragma unroll
                for (int r4 = 0; r4 < OCW / 4; ++r4) wr[r4] = wv[r4];
                const float* lw = (const float*)wr;
                #pragma unroll
                for (int j = 0; j < J; ++j) {
                    float iv = lds[ic * PST + pbase[j] + kh * PW + kw];
                    #pragma unroll
                    for (int o = 0; o < OCW; ++o) acc[j * OCW + o] += iv * lw[o];
                }
            }
        }
    }
    if (lane < 49) {
        #pragma unroll
        for (int j = 0; j < J; ++j) {
            int g = (CO == OCW) ? (wave * J + j) : j;
            int px = g * 49 + lane;
            #pragma unroll
            for (int o = 0; o < OCW; ++o)
                out[((size_t)tn * CO + oc0 + o) * (HO * WO) + px] = acc[j * OCW + o];
        }
    }
}

// ---- fused: spike(x4 columns) -> 2x2 pool -> psp -> spike -> psp, prefetched
template<int C, int HI, int WI>
__global__ void k_fuse_pool(const float* __restrict__ U, float* __restrict__ X) {
    constexpr int HO = HI / 2, WO = WI / 2;
    constexpr int M   = NB * C * HO * WO;
    constexpr int NSI = NB * C * HI * WI;
    int i = blockIdx.x * blockDim.x + threadIdx.x;
    if (i >= M) return;
    int j = i % WO, r = (i / WO) % HO, nc = i / (WO * HO);
    size_t base = (size_t)(nc * HI + 2 * r) * WI + 2 * j;
    const float2* R0 = (const float2*)(U + base);
    const float2* R1 = (const float2*)(U + base + WI);
    constexpr int G = 10, NG = TT / G;
    float2 A0[G], A1[G], B0[G], B1[G];
    #pragma unroll
    for (int u = 0; u < G; ++u) {
        A0[u] = R0[(size_t)u * (NSI / 2)];
        A1[u] = R1[(size_t)u * (NSI / 2)];
    }
    float p00=0,q00=0,p01=0,q01=0,p10=0,q10=0,p11=0,q11=0;
    float P=0,Q=0, sp=0,sq=0, P2=0,Q2=0;
    for (int g = 0; g < NG; ++g) {
        if (g + 1 < NG) {
            #pragma unroll
            for (int u = 0; u < G; ++u) {
                B0[u] = R0[(size_t)((g + 1) * G + u) * (NSI / 2)];
                B1[u] = R1[(size_t)((g + 1) * G + u) * (NSI / 2)];
            }
        }
        #pragma unroll
        for (int u = 0; u < G; ++u) {
            int t = g * G + u;
            float s0, s1, s2, s3;
            q00 = D_RF*(q00+p00); { float v = A0[u].x + A_RF*q00; s0 = (v>=THETA_F)?1.f:0.f; } p00 = D_RF*p00+s0;
            q01 = D_RF*(q01+p01); { float v = A0[u].y + A_RF*q01; s1 = (v>=THETA_F)?1.f:0.f; } p01 = D_RF*p01+s1;
            q10 = D_RF*(q10+p10); { float v = A1[u].x + A_RF*q10; s2 = (v>=THETA_F)?1.f:0.f; } p10 = D_RF*p10+s2;
            q11 = D_RF*(q11+p11); { float v = A1[u].y + A_RF*q11; s3 = (v>=THETA_F)?1.f:0.f; } p11 = D_RF*p11+s3;
            float x = (s0 + s1 + s2 + s3) * PGAIN;
            Q = D_SR*(Q+P); P = D_SR*P + x; float drive = B_SR*Q;
            sq = D_RF*(sq+sp); float v2 = drive + A_RF*sq; float sv = (v2>=THETA_F)?1.f:0.f; sp = D_RF*sp+sv;
            Q2 = D_SR*(Q2+P2); P2 = D_SR*P2 + sv;
            X[(size_t)t * M + i] = B_SR * Q2;
        }
        #pragma unroll
        for (int u = 0; u < G; ++u) { A0[u] = B0[u]; A1[u] = B1[u]; }
    }
}

// ---- fused spike -> psp, out-of-place, prefetched
__global__ void k_spike_psp(const float* __restrict__ U, float* __restrict__ X, int NS) {
    int i = blockIdx.x * blockDim.x + threadIdx.x;
    if (i >= NS) return;
    constexpr int G = 20, NG = TT / G;
    float A[G], B[G];
    #pragma unroll
    for (int u = 0; u < G; ++u) A[u] = U[(size_t)u * NS + i];
    float p = 0, q = 0, P = 0, Q = 0;
    for (int g = 0; g < NG; ++g) {
        if (g + 1 < NG) {
            #pragma unroll
            for (int u = 0; u < G; ++u) B[u] = U[(size_t)((g + 1) * G + u) * NS + i];
        }
        #pragma unroll
        for (int u = 0; u < G; ++u) {
            int t = g * G + u;
            q = D_RF * (q + p);
            float v = A[u] + A_RF * q;
            float s = (v >= THETA_F) ? 1.f : 0.f;
            p = D_RF * p + s;
            Q = D_SR * (Q + P); P = D_SR * P + s;
            X[(size_t)t * NS + i] = B_SR * Q;
        }
        #pragma unroll
        for (int u = 0; u < G; ++u) A[u] = B[u];
    }
}

// ---- dense: one wave per (t,n); coalesced loads + shuffle reduce
__global__ void k_dense(const float* __restrict__ X, const float* __restrict__ wf,
                        float* __restrict__ G_) {
    int tn = blockIdx.x;                 // 0..2399
    int lane = threadIdx.x;              // 0..63
    const float* xb = X + (size_t)tn * 3136;
    float acc[10];
    #pragma unroll
    for (int o = 0; o < 10; ++o) acc[o] = 0.f;
    for (int it = 0; it < 49; ++it) {
        int k = it * 64 + lane;
        float xv = xb[k];
        #pragma unroll
        for (int o = 0; o < 10; ++o) acc[o] += xv * wf[o * 3136 + k];
    }
    #pragma unroll
    for (int off = 32; off > 0; off >>= 1) {
        #pragma unroll
        for (int o = 0; o < 10; ++o) acc[o] += __shfl_down(acc[o], off);
    }
    if (lane == 0) {
        #pragma unroll
        for (int o = 0; o < 10; ++o) G_[tn * 10 + o] = acc[o];
    }
}

// ---- final spike on [T][80] -> out [N][10][T], prefetched
__global__ void k_spike_out(const float* __restrict__ G_, float* __restrict__ out) {
    int i = threadIdx.x;
    if (i >= 80) return;
    constexpr int G = 20, NG = TT / G;
    float A[G], B[G];
    #pragma unroll
    for (int u = 0; u < G; ++u) A[u] = G_[u * 80 + i];
    float p = 0, q = 0;
    for (int g = 0; g < NG; ++g) {
        if (g + 1 < NG) {
            #pragma unroll
            for (int u = 0; u < G; ++u) B[u] = G_[((g + 1) * G + u) * 80 + i];
        }
        #pragma unroll
        for (int u = 0; u < G; ++u) {
            int t = g * G + u;
            q = D_RF * (q + p);
            float v = A[u] + A_RF * q;
            float s = (v >= THETA_F) ? 1.f : 0.f;
            p = D_RF * p + s;
            out[(size_t)i * TT + t] = s;
        }
        #pragma unroll
        for (int u = 0; u < G; ++u) A[u] = B[u];
    }
}

static inline int cdiv(int a, int b) { return (a + b - 1) / b; }

extern "C" void kernel_launch(void* const* d_in, const int* in_sizes, int n_in,
                              void* d_out, int out_size, void* d_ws, size_t ws_size,
                              hipStream_t stream) {
    const float* x  = (const float*)d_in[0];   // [8,1,30,30,300]
    const float* w1 = (const float*)d_in[1];   // [16,1,5,5]
    const float* w2 = (const float*)d_in[2];   // [32,16,3,3]
    const float* w3 = (const float*)d_in[3];   // [64,32,3,3]
    const float* wf = (const float*)d_in[4];   // [10,64,7,7]
    float* out = (float*)d_out;                // [8,10,300]
    float* ws  = (float*)d_ws;

    // workspace (floats): total 39,839,440 = 159.4 MB
    float* A   = ws;                    // [300][7200]
    float* U1  = ws + 2160000;          // [300][100352] conv1 out (120 MB slot)
    float* X2  = ws + 32265600;         // [300][25088]
    float* Gg  = ws + 39792000;         // [300][80]
    float* wT1 = ws + 39816000;         // [25][16]
    float* wT2 = ws + 39816400;         // [144][32]
    float* wT3 = ws + 39821008;         // [288][64]
    // aliases (lifetime-disjoint, all inside U1/X2 slots)
    float* U2  = U1;                    // [300][50176] (60 MB)
    float* X4  = U1 + 16000000;         // [300][12544] (15 MB)
    float* U3  = X2;                    // [300][25088]
    float* X5  = U1;                    // [300][25088] (30 MB, disjoint from X4)

    const int B = 256;
    k_wtr<<<cdiv(23440, B), B, 0, stream>>>(w1, w2, w3, wT1, wT2, wT3);
    k_psp_tr<<<cdiv(7200, B), B, 0, stream>>>(x, A, 7200);
    // conv1: 1->16, 5x5 pad1, 30x30 -> 28x28 (784 px = 16 groups of 49)
    k_conv<1, 16, 5, 30, 30, 28, 28, 16, 4><<<2400, B, 0, stream>>>(A, wT1, U1);
    // spike x4 -> pool -> psp -> spike -> psp
    k_fuse_pool<16, 28, 28><<<cdiv(25088, B), B, 0, stream>>>(U1, X2);
    // conv2: 16->32, 3x3 pad1, 14x14 (196 px = 4 groups)
    k_conv<16, 32, 3, 14, 14, 14, 14, 32, 1><<<2400, B, 0, stream>>>(X2, wT2, U2);
    k_fuse_pool<32, 14, 14><<<cdiv(12544, B), B, 0, stream>>>(U2, X4);
    // conv3: 32->64, 3x3 pad1, 7x7 (49 px, 4 waves x 16 oc)
    k_conv<32, 64, 3, 7, 7, 7, 7, 16, 1><<<2400, B, 0, stream>>>(X4, wT3, U3);
    k_spike_psp<<<cdiv(25088, B), B, 0, stream>>>(U3, X5, 25088);
    k_dense<<<2400, 64, 0, stream>>>(X5, wf, Gg);
    k_spike_out<<<1, 128, 0, stream>>>(Gg, out);
}